// Round 1
// baseline (359.263 us; speedup 1.0000x reference)
//
#include <hip/hip_runtime.h>

// Problem constants: B=8, S=512, F=64, H=256  ->  BS = 4096 rows
#define NBS 4096

typedef __attribute__((ext_vector_type(8))) short short8v;   // 8 bf16 (4 VGPR)
typedef __attribute__((ext_vector_type(4))) float f32x4;

static __device__ __forceinline__ unsigned short f2bf(float f) {
    unsigned int u = __float_as_uint(f);
    unsigned int r = u + 0x7fffu + ((u >> 16) & 1u);   // RNE
    return (unsigned short)(r >> 16);
}
static __device__ __forceinline__ float sigm(float v) {
    return 1.f / (1.f + __expf(-v));
}

// ---------------------------------------------------------------------------
// Kernel 0: convert f_fc2_w [512,256] fp32 -> bf16 (row-major, = B^T layout)
// ---------------------------------------------------------------------------
__global__ void k_conv_w2(const float* __restrict__ w2, unsigned short* __restrict__ w2b) {
    int i = blockIdx.x * 256 + threadIdx.x;   // grid 512*256 = 131072 elems
    w2b[i] = f2bf(w2[i]);
}

// ---------------------------------------------------------------------------
// Kernel 1: weight GRN + softmax  ->  wts[4096][64]
// one block (64 threads = 1 wave) per (b,s) row
// ---------------------------------------------------------------------------
__global__ void k_wgrn(const float* __restrict__ x,
                       const float* __restrict__ fc1w, const float* __restrict__ fc1b,
                       const float* __restrict__ fc2w, const float* __restrict__ fc2b,
                       const float* __restrict__ lng,  const float* __restrict__ lnb,
                       float* __restrict__ wts) {
    __shared__ float xs[64];
    __shared__ float hs[64];
    const int bs = blockIdx.x;
    const int t  = threadIdx.x;

    float xv = x[bs * 64 + t];
    xs[t] = xv;
    __syncthreads();

    // fc1 row t + elu
    float acc = fc1b[t];
    const float* wr = fc1w + t * 64;
    #pragma unroll 8
    for (int k = 0; k < 64; ++k) acc = fmaf(xs[k], wr[k], acc);
    hs[t] = acc > 0.f ? acc : expm1f(acc);
    __syncthreads();

    // fc2 rows t and t+64 (GLU halves)
    float d1 = fc2b[t], d2 = fc2b[t + 64];
    const float* w1r = fc2w + t * 64;
    const float* w2r = fc2w + (t + 64) * 64;
    #pragma unroll 8
    for (int k = 0; k < 64; ++k) {
        float hk = hs[k];
        d1 = fmaf(hk, w1r[k], d1);
        d2 = fmaf(hk, w2r[k], d2);
    }
    float y = xv + d1 * sigm(d2);   // identity skip + GLU

    // LayerNorm over 64 lanes
    float s = y, s2 = y * y;
    #pragma unroll
    for (int m = 1; m < 64; m <<= 1) { s += __shfl_xor(s, m); s2 += __shfl_xor(s2, m); }
    float mu  = s * (1.f / 64.f);
    float var = s2 * (1.f / 64.f) - mu * mu;
    float g   = (y - mu) * rsqrtf(var + 1e-5f) * lng[t] + lnb[t];

    // softmax over 64 lanes
    float mx = g;
    #pragma unroll
    for (int m = 1; m < 64; m <<= 1) mx = fmaxf(mx, __shfl_xor(mx, m));
    float e = __expf(g - mx);
    float se = e;
    #pragma unroll
    for (int m = 1; m < 64; m <<= 1) se += __shfl_xor(se, m);
    wts[bs * 64 + t] = e / se;
}

// ---------------------------------------------------------------------------
// Kernel 2: feature GRN (MFMA GEMM) + LN + weighted feature-sum
// one block per (b,s): M=64 (f), N=512 (2H), K=256 (H); 8 waves
// wave w owns cols [32w,32w+32) (h1 half) and [256+32w, 256+32w+32) (h2 half)
// ---------------------------------------------------------------------------
__global__ __launch_bounds__(512) void k_vsn_main(
        const float* __restrict__ x,
        const unsigned short* __restrict__ w2b,   // bf16 f_fc2_w [512][256]
        const float* __restrict__ f1w, const float* __restrict__ f1b,
        const float* __restrict__ f2b,
        const float* __restrict__ lng, const float* __restrict__ lnb,
        const float* __restrict__ skw, const float* __restrict__ skb,
        const float* __restrict__ wts,
        float* __restrict__ out) {
    __shared__ __align__(16) unsigned short aS[64 * 256];  // bf16 A, XOR-swizzled, 32 KB
    __shared__ float xsh[64];
    __shared__ float red[8][64][2];    // per-wave partial (sum, sumsq) per row
    __shared__ float rowstat[64][2];   // (mu, wt*rstd) per row
    __shared__ float TsumS;

    const int bs  = blockIdx.x;
    const int tid = threadIdx.x;
    const float* xrow = x + bs * 64;

    if (tid < 64) xsh[tid] = xrow[tid];

    // ---- Phase 1: generate A[f][k] = elu(x_f * w1[k] + b1[k]) as bf16 in LDS.
    // Swizzle: 8-bf16 chunk index kc stored at (kc ^ (f&7)) -> conflict-free
    // ds_read_b128 fragment reads later (8-lane groups cover all 8 bank slots).
    {
        const int f  = tid >> 3;       // 0..63
        const int c0 = tid & 7;        // chunk 0..7 (+8i)
        const float xf = xrow[f];
        const int fx = f & 7;
        #pragma unroll
        for (int i = 0; i < 4; ++i) {
            const int c  = c0 + 8 * i;   // 0..31
            const int kb = c * 8;
            short8v v;
            #pragma unroll
            for (int j = 0; j < 8; ++j) {
                float t = fmaf(xf, f1w[kb + j], f1b[kb + j]);
                float e = t > 0.f ? t : expm1f(t);
                v[j] = (short)f2bf(e);
            }
            *(short8v*)(&aS[f * 256 + (c ^ fx) * 8]) = v;
        }
    }
    __syncthreads();

    // ---- Phase 2: MFMA GEMM  h2v[64f][64n-slice] per wave
    const int lane = tid & 63;
    const int wave = tid >> 6;
    const int lc = lane & 15;
    const int lg = lane >> 4;

    f32x4 acc[4][4];   // [row-tile][q: 0,1 = h1 cols, 2,3 = h2 cols]
    #pragma unroll
    for (int a = 0; a < 4; ++a)
        #pragma unroll
        for (int b = 0; b < 4; ++b)
            acc[a][b] = (f32x4){0.f, 0.f, 0.f, 0.f};

    // B fragment base: col = colbase + lc, k-offset lg*8 (contiguous in w2b row)
    const unsigned short* bp = w2b + (wave * 32 + lc) * 256 + lg * 8;
    const int q_off[4] = {0, 16 * 256, 256 * 256, 272 * 256};

    for (int ks = 0; ks < 8; ++ks) {
        const int kc  = ks * 4 + lg;                 // 8-elem chunk index 0..31
        const int scx = ((kc ^ (lc & 7))) * 8;       // swizzled (f&7 == lc&7)
        short8v af[4];
        #pragma unroll
        for (int rt = 0; rt < 4; ++rt)
            af[rt] = *(const short8v*)(&aS[(rt * 16 + lc) * 256 + scx]);
        short8v bf[4];
        #pragma unroll
        for (int q = 0; q < 4; ++q)
            bf[q] = *(const short8v*)(bp + q_off[q] + ks * 32);
        #pragma unroll
        for (int rt = 0; rt < 4; ++rt)
            #pragma unroll
            for (int q = 0; q < 4; ++q)
                acc[rt][q] = __builtin_amdgcn_mfma_f32_16x16x32_bf16(
                                 af[rt], bf[q], acc[rt][q], 0, 0, 0);
    }

    // ---- Phase 3: GLU + residual -> y; per-row partial sums
    const int h0  = wave * 32 + lc;        // H-index of q=0/2 col
    const int h1i = h0 + 16;               // H-index of q=1/3 col
    const float skw0 = skw[h0],  skb0 = skb[h0];
    const float skw1 = skw[h1i], skb1 = skb[h1i];
    const float b2a0 = f2b[h0],        b2a1 = f2b[h1i];
    const float b2g0 = f2b[256 + h0],  b2g1 = f2b[256 + h1i];

    float y0[4][4], y1[4][4];
    #pragma unroll
    for (int rt = 0; rt < 4; ++rt) {
        #pragma unroll
        for (int r = 0; r < 4; ++r) {
            const int f = rt * 16 + lg * 4 + r;    // C/D row = (lane>>4)*4 + reg
            const float xf = xsh[f];
            float g1 = acc[rt][0][r] + b2a0;
            float g2 = acc[rt][2][r] + b2g0;
            float yy0 = fmaf(xf, skw0, skb0) + g1 * sigm(g2);
            float g3 = acc[rt][1][r] + b2a1;
            float g4 = acc[rt][3][r] + b2g1;
            float yy1 = fmaf(xf, skw1, skb1) + g3 * sigm(g4);
            y0[rt][r] = yy0;
            y1[rt][r] = yy1;
            float ps  = yy0 + yy1;
            float ps2 = yy0 * yy0 + yy1 * yy1;
            #pragma unroll
            for (int m = 1; m < 16; m <<= 1) {
                ps  += __shfl_xor(ps, m);
                ps2 += __shfl_xor(ps2, m);
            }
            if (lc == 0) { red[wave][f][0] = ps; red[wave][f][1] = ps2; }
        }
    }
    __syncthreads();

    // ---- Phase 4: per-row stats (threads 0..63 = wave 0)
    if (tid < 64) {
        float s = 0.f, s2 = 0.f;
        #pragma unroll
        for (int w = 0; w < 8; ++w) { s += red[w][tid][0]; s2 += red[w][tid][1]; }
        float mu  = s * (1.f / 256.f);
        float var = s2 * (1.f / 256.f) - mu * mu;
        float rstd = rsqrtf(var + 1e-5f);
        float wf = wts[bs * 64 + tid];
        rowstat[tid][0] = mu;
        rowstat[tid][1] = wf * rstd;
        float ts = wf;
        #pragma unroll
        for (int m = 1; m < 64; m <<= 1) ts += __shfl_xor(ts, m);
        if (tid == 0) TsumS = ts;
    }
    __syncthreads();

    // ---- Phase 5: weighted feature-sum, fold LN affine:
    // out[h] = g[h] * sum_f wt_f*rstd_f*(y[f,h]-mu_f) + b[h] * sum_f wt_f
    float S0 = 0.f, S1 = 0.f;
    #pragma unroll
    for (int rt = 0; rt < 4; ++rt) {
        #pragma unroll
        for (int r = 0; r < 4; ++r) {
            const int f = rt * 16 + lg * 4 + r;
            const float mu = rowstat[f][0];
            const float sf = rowstat[f][1];
            S0 = fmaf(sf, y0[rt][r] - mu, S0);
            S1 = fmaf(sf, y1[rt][r] - mu, S1);
        }
    }
    S0 += __shfl_xor(S0, 16); S0 += __shfl_xor(S0, 32);
    S1 += __shfl_xor(S1, 16); S1 += __shfl_xor(S1, 32);

    if (lg == 0) {
        const float T = TsumS;
        out[bs * 256 + h0]  = fmaf(lng[h0],  S0, lnb[h0]  * T);
        out[bs * 256 + h1i] = fmaf(lng[h1i], S1, lnb[h1i] * T);
    }
}

// ---------------------------------------------------------------------------
extern "C" void kernel_launch(void* const* d_in, const int* in_sizes, int n_in,
                              void* d_out, int out_size, void* d_ws, size_t ws_size,
                              hipStream_t stream) {
    const float* x    = (const float*)d_in[0];
    const float* wf1w = (const float*)d_in[1];
    const float* wf1b = (const float*)d_in[2];
    const float* wf2w = (const float*)d_in[3];
    const float* wf2b = (const float*)d_in[4];
    const float* wlng = (const float*)d_in[5];
    const float* wlnb = (const float*)d_in[6];
    const float* ff1w = (const float*)d_in[7];
    const float* ff1b = (const float*)d_in[8];
    const float* ff2w = (const float*)d_in[9];
    const float* ff2b = (const float*)d_in[10];
    const float* flng = (const float*)d_in[11];
    const float* flnb = (const float*)d_in[12];
    const float* fskw = (const float*)d_in[13];
    const float* fskb = (const float*)d_in[14];

    float* wts = (float*)d_ws;                                      // 4096*64 fp32 = 1 MB
    unsigned short* w2b = (unsigned short*)((char*)d_ws + NBS * 64 * sizeof(float)); // 256 KB

    k_conv_w2<<<512, 256, 0, stream>>>(ff2w, w2b);
    k_wgrn<<<NBS, 64, 0, stream>>>(x, wf1w, wf1b, wf2w, wf2b, wlng, wlnb, wts);
    k_vsn_main<<<NBS, 512, 0, stream>>>(x, w2b, ff1w, ff1b, ff2b,
                                        flng, flnb, fskw, fskb, wts, (float*)d_out);
}

// Round 2
// 196.852 us; speedup vs baseline: 1.8250x; 1.8250x over previous
//
#include <hip/hip_runtime.h>

// Problem constants: B=8, S=512, F=64, H=256  ->  BS = 4096 rows
#define NBS  4096
#define ROWS 16                  // (b,s) rows per persistent block
#define NBLK (NBS / ROWS)        // 256 blocks = 1 per CU

typedef __attribute__((ext_vector_type(8))) short short8v;   // 8 bf16 (4 VGPR)
typedef __attribute__((ext_vector_type(4))) float f32x4;

static __device__ __forceinline__ unsigned short f2bf(float f) {
    unsigned int u = __float_as_uint(f);
    unsigned int r = u + 0x7fffu + ((u >> 16) & 1u);   // RNE
    return (unsigned short)(r >> 16);
}
static __device__ __forceinline__ float sigm(float v) {
    return 1.f / (1.f + __expf(-v));
}
static __device__ __forceinline__ float elu_fast(float t) {
    return t > 0.f ? t : __expf(t) - 1.f;
}

// ---------------------------------------------------------------------------
// Kernel 0: convert f_fc2_w [512,256] fp32 -> bf16 (row-major, = B^T layout)
// ---------------------------------------------------------------------------
__global__ void k_conv_w2(const float* __restrict__ w2, unsigned short* __restrict__ w2b) {
    int i = blockIdx.x * 256 + threadIdx.x;
    w2b[i] = f2bf(w2[i]);
}

// ---------------------------------------------------------------------------
// Kernel 1: weight GRN + softmax  ->  wts[4096][64]; 1 wave per (b,s) row
// ---------------------------------------------------------------------------
__global__ void k_wgrn(const float* __restrict__ x,
                       const float* __restrict__ fc1w, const float* __restrict__ fc1b,
                       const float* __restrict__ fc2w, const float* __restrict__ fc2b,
                       const float* __restrict__ lng,  const float* __restrict__ lnb,
                       float* __restrict__ wts) {
    __shared__ float xs[64];
    __shared__ float hs[64];
    const int bs = blockIdx.x;
    const int t  = threadIdx.x;

    float xv = x[bs * 64 + t];
    xs[t] = xv;
    __syncthreads();

    float acc = fc1b[t];
    const float4* wr = (const float4*)(fc1w + t * 64);
    #pragma unroll
    for (int k = 0; k < 16; ++k) {
        float4 w = wr[k];
        const float* xp = &xs[k * 4];
        acc = fmaf(xp[0], w.x, acc); acc = fmaf(xp[1], w.y, acc);
        acc = fmaf(xp[2], w.z, acc); acc = fmaf(xp[3], w.w, acc);
    }
    hs[t] = elu_fast(acc);
    __syncthreads();

    float d1 = fc2b[t], d2 = fc2b[t + 64];
    const float4* w1r = (const float4*)(fc2w + t * 64);
    const float4* w2r = (const float4*)(fc2w + (t + 64) * 64);
    #pragma unroll
    for (int k = 0; k < 16; ++k) {
        float4 a = w1r[k], b = w2r[k];
        const float* hp = &hs[k * 4];
        d1 = fmaf(hp[0], a.x, d1); d1 = fmaf(hp[1], a.y, d1);
        d1 = fmaf(hp[2], a.z, d1); d1 = fmaf(hp[3], a.w, d1);
        d2 = fmaf(hp[0], b.x, d2); d2 = fmaf(hp[1], b.y, d2);
        d2 = fmaf(hp[2], b.z, d2); d2 = fmaf(hp[3], b.w, d2);
    }
    float y = xv + d1 * sigm(d2);

    float s = y, s2 = y * y;
    #pragma unroll
    for (int m = 1; m < 64; m <<= 1) { s += __shfl_xor(s, m); s2 += __shfl_xor(s2, m); }
    float mu  = s * (1.f / 64.f);
    float var = s2 * (1.f / 64.f) - mu * mu;
    float g   = (y - mu) * rsqrtf(var + 1e-5f) * lng[t] + lnb[t];

    float mx = g;
    #pragma unroll
    for (int m = 1; m < 64; m <<= 1) mx = fmaxf(mx, __shfl_xor(mx, m));
    float e = __expf(g - mx);
    float se = e;
    #pragma unroll
    for (int m = 1; m < 64; m <<= 1) se += __shfl_xor(se, m);
    wts[bs * 64 + t] = e / se;
}

// ---------------------------------------------------------------------------
// A-tile generation: A[f][k] = elu(x_f * w1[k] + b1[k]) as bf16, XOR-swizzled
// chunk layout (chunk kc stored at kc ^ (f&7)) for conflict-free frag reads.
// ---------------------------------------------------------------------------
static __device__ __forceinline__ void gen_row(unsigned short* __restrict__ dst,
                                               const float* __restrict__ xrow,
                                               const float* __restrict__ wsh,
                                               const float* __restrict__ bsh,
                                               int tid) {
    const int f  = tid >> 3;       // 0..63
    const int c0 = tid & 7;
    const int fx = f & 7;
    const float xf = xrow[f];
    #pragma unroll
    for (int i = 0; i < 4; ++i) {
        const int c  = c0 + 8 * i;   // chunk 0..31
        const int kb = c * 8;
        short8v v;
        #pragma unroll
        for (int j = 0; j < 8; ++j) {
            float t = fmaf(xf, wsh[kb + j], bsh[kb + j]);
            v[j] = (short)f2bf(elu_fast(t));
        }
        *(short8v*)(dst + f * 256 + (c ^ fx) * 8) = v;
    }
}

// ---------------------------------------------------------------------------
// Kernel 2: persistent feature-GRN GEMM. 256 blocks x 512 thr; 16 rows each.
// B (f_fc2_w bf16) held entirely in registers (128 VGPR/lane), loaded once.
// Per row: M=64(f), N=512(2H), K=256; wave w owns cols [32w,32w+32) of each
// GLU half; A double-buffered in LDS so gen(r+1) overlaps MFMA(r).
// ---------------------------------------------------------------------------
__global__ __launch_bounds__(512, 2) void k_vsn_main(
        const float* __restrict__ x,
        const unsigned short* __restrict__ w2b,   // bf16 f_fc2_w [512][256]
        const float* __restrict__ f1w, const float* __restrict__ f1b,
        const float* __restrict__ f2b,
        const float* __restrict__ lng, const float* __restrict__ lnb,
        const float* __restrict__ skw, const float* __restrict__ skb,
        const float* __restrict__ wts,
        float* __restrict__ out) {
    __shared__ __align__(16) unsigned short aS[2][64 * 256];  // 2 x 32 KB
    __shared__ float wsh[256], bsh[256];
    __shared__ float xsh[ROWS * 64];
    __shared__ float wtsh[ROWS * 64];
    __shared__ float red[8][64][2];
    __shared__ float rowstat[64][2];
    __shared__ float TsumS;

    const int tid = threadIdx.x;
    const int bs0 = blockIdx.x * ROWS;

    if (tid < 256) { wsh[tid] = f1w[tid]; bsh[tid] = f1b[tid]; }
    xsh[tid]        = x[bs0 * 64 + tid];
    xsh[tid + 512]  = x[bs0 * 64 + tid + 512];
    wtsh[tid]       = wts[bs0 * 64 + tid];
    wtsh[tid + 512] = wts[bs0 * 64 + tid + 512];

    const int lane = tid & 63;
    const int wave = tid >> 6;
    const int lc = lane & 15;
    const int lg = lane >> 4;

    // ---- preload all B fragments (once per kernel)
    short8v Breg[8][4];
    {
        const unsigned short* bp = w2b + (wave * 32 + lc) * 256 + lg * 8;
        const int q_off[4] = {0, 16 * 256, 256 * 256, 272 * 256};
        #pragma unroll
        for (int ks = 0; ks < 8; ++ks)
            #pragma unroll
            for (int q = 0; q < 4; ++q)
                Breg[ks][q] = *(const short8v*)(bp + q_off[q] + ks * 32);
    }

    // per-column constants (cols h0, h0+16 of each GLU half)
    const int h0  = wave * 32 + lc;
    const int h1i = h0 + 16;
    const float skw0 = skw[h0],  skb0 = skb[h0];
    const float skw1 = skw[h1i], skb1 = skb[h1i];
    const float b2a0 = f2b[h0],        b2a1 = f2b[h1i];
    const float b2g0 = f2b[256 + h0],  b2g1 = f2b[256 + h1i];
    const float lg0 = lng[h0], lg1 = lng[h1i];
    const float lb0 = lnb[h0], lb1 = lnb[h1i];

    __syncthreads();
    gen_row(aS[0], &xsh[0], wsh, bsh, tid);
    __syncthreads();

    for (int r = 0; r < ROWS; ++r) {
        const int cur = r & 1;
        unsigned short* aCur = aS[cur];

        // ---- GEMM: acc[rt][q], B from registers, A frags broadcast-read
        f32x4 acc[4][4];
        #pragma unroll
        for (int a = 0; a < 4; ++a)
            #pragma unroll
            for (int b = 0; b < 4; ++b)
                acc[a][b] = (f32x4){0.f, 0.f, 0.f, 0.f};

        #pragma unroll
        for (int ks = 0; ks < 8; ++ks) {
            const int scx = (((ks * 4 + lg)) ^ (lc & 7)) * 8;
            short8v af[4];
            #pragma unroll
            for (int rt = 0; rt < 4; ++rt)
                af[rt] = *(const short8v*)(&aCur[(rt * 16 + lc) * 256 + scx]);
            #pragma unroll
            for (int rt = 0; rt < 4; ++rt)
                #pragma unroll
                for (int q = 0; q < 4; ++q)
                    acc[rt][q] = __builtin_amdgcn_mfma_f32_16x16x32_bf16(
                                     af[rt], Breg[ks][q], acc[rt][q], 0, 0, 0);
        }

        // ---- generate next row's A while MFMAs drain (independent ops)
        if (r + 1 < ROWS)
            gen_row(aS[cur ^ 1], &xsh[(r + 1) * 64], wsh, bsh, tid);

        // ---- GLU + residual -> y; per-row partial (sum, sumsq)
        float y0[4][4], y1[4][4];
        #pragma unroll
        for (int rt = 0; rt < 4; ++rt) {
            #pragma unroll
            for (int rr = 0; rr < 4; ++rr) {
                const int f = rt * 16 + lg * 4 + rr;    // C/D row mapping
                const float xf = xsh[r * 64 + f];
                float a1 = acc[rt][0][rr] + b2a0;
                float a2 = acc[rt][2][rr] + b2g0;
                float yy0 = fmaf(xf, skw0, skb0) + a1 * sigm(a2);
                float a3 = acc[rt][1][rr] + b2a1;
                float a4 = acc[rt][3][rr] + b2g1;
                float yy1 = fmaf(xf, skw1, skb1) + a3 * sigm(a4);
                y0[rt][rr] = yy0;
                y1[rt][rr] = yy1;
                float ps  = yy0 + yy1;
                float ps2 = yy0 * yy0 + yy1 * yy1;
                #pragma unroll
                for (int m = 1; m < 16; m <<= 1) {
                    ps  += __shfl_xor(ps, m);
                    ps2 += __shfl_xor(ps2, m);
                }
                if (lc == 0) { red[wave][f][0] = ps; red[wave][f][1] = ps2; }
            }
        }
        __syncthreads();

        // ---- per-row stats (wave 0)
        if (tid < 64) {
            float s = 0.f, s2 = 0.f;
            #pragma unroll
            for (int w = 0; w < 8; ++w) {
                float2 p = *(const float2*)&red[w][tid][0];
                s += p.x; s2 += p.y;
            }
            float mu  = s * (1.f / 256.f);
            float var = s2 * (1.f / 256.f) - mu * mu;
            float rstd = rsqrtf(var + 1e-5f);
            float wf = wtsh[r * 64 + tid];
            rowstat[tid][0] = mu;
            rowstat[tid][1] = wf * rstd;
            float ts = wf;
            #pragma unroll
            for (int m = 1; m < 64; m <<= 1) ts += __shfl_xor(ts, m);
            if (tid == 0) TsumS = ts;
        }
        __syncthreads();

        // ---- weighted feature-sum with folded LN affine
        float S0 = 0.f, S1 = 0.f;
        #pragma unroll
        for (int rt = 0; rt < 4; ++rt) {
            #pragma unroll
            for (int rr = 0; rr < 4; ++rr) {
                const int f = rt * 16 + lg * 4 + rr;
                const float mu = rowstat[f][0];
                const float sf = rowstat[f][1];
                S0 = fmaf(sf, y0[rt][rr] - mu, S0);
                S1 = fmaf(sf, y1[rt][rr] - mu, S1);
            }
        }
        S0 += __shfl_xor(S0, 16); S0 += __shfl_xor(S0, 32);
        S1 += __shfl_xor(S1, 16); S1 += __shfl_xor(S1, 32);

        if (lg == 0) {
            const float T = TsumS;
            float* orow = out + (bs0 + r) * 256;
            orow[h0]  = fmaf(lg0, S0, lb0 * T);
            orow[h1i] = fmaf(lg1, S1, lb1 * T);
        }
    }
}

// ---------------------------------------------------------------------------
extern "C" void kernel_launch(void* const* d_in, const int* in_sizes, int n_in,
                              void* d_out, int out_size, void* d_ws, size_t ws_size,
                              hipStream_t stream) {
    const float* x    = (const float*)d_in[0];
    const float* wf1w = (const float*)d_in[1];
    const float* wf1b = (const float*)d_in[2];
    const float* wf2w = (const float*)d_in[3];
    const float* wf2b = (const float*)d_in[4];
    const float* wlng = (const float*)d_in[5];
    const float* wlnb = (const float*)d_in[6];
    const float* ff1w = (const float*)d_in[7];
    const float* ff1b = (const float*)d_in[8];
    const float* ff2w = (const float*)d_in[9];
    const float* ff2b = (const float*)d_in[10];
    const float* flng = (const float*)d_in[11];
    const float* flnb = (const float*)d_in[12];
    const float* fskw = (const float*)d_in[13];
    const float* fskb = (const float*)d_in[14];

    float* wts = (float*)d_ws;                                      // 1 MB
    unsigned short* w2b = (unsigned short*)((char*)d_ws + NBS * 64 * sizeof(float)); // 256 KB

    k_conv_w2<<<512, 256, 0, stream>>>(ff2w, w2b);
    k_wgrn<<<NBS, 64, 0, stream>>>(x, wf1w, wf1b, wf2w, wf2b, wlng, wlnb, wts);
    k_vsn_main<<<NBLK, 512, 0, stream>>>(x, w2b, ff1w, ff1b, ff2b,
                                         flng, flnb, fskw, fskb, wts, (float*)d_out);
}